// Round 8
// baseline (515.043 us; speedup 1.0000x reference)
//
#include <hip/hip_runtime.h>

#define SEQ 128
#define HID 32
#define TPB 256   // 4 waves, 16 nodes per block, gate-split across waves
#define XS 56     // LDS row stride in shorts: 112B = 7*16B (16B-aligned b128 rows)
#define PS 20     // pre[] inner stride (floats): write bank (16q+n)%32, read (8q+n)%32 -> <=2-way

typedef __attribute__((ext_vector_type(8))) short short8;   // 8 bf16 = 4 VGPR
typedef __attribute__((ext_vector_type(4))) float floatx4;  // MFMA acc

// ---------------- GCN prep (identical to round-5 verified version) ----------------

__global__ void count_kernel(const int* __restrict__ idx, int E, int* __restrict__ cnt) {
    int e = (blockIdx.x * blockDim.x + threadIdx.x) * 4;
    if (((E & 3) == 0) && e + 3 < E) {
        int4 d = *(const int4*)(idx + E + e);   // 16B aligned: E%4==0, e%4==0
        atomicAdd(&cnt[d.x], 1);
        atomicAdd(&cnt[d.y], 1);
        atomicAdd(&cnt[d.z], 1);
        atomicAdd(&cnt[d.w], 1);
    } else {
        int lim = min(e + 4, E);
        for (int k = e; k < lim; ++k) atomicAdd(&cnt[idx[E + k]], 1);
    }
}

// Fixed-point pack: q = rn(v * 2^21), biased +2^26 per 32b field -> every added term
// positive and < 2^26.2, no cross-field carry up to ~56 adds. ONE u64 atomic per
// edge; dinv[src] computed inline from the deg gather (scatter is atomic-rate-bound).
__device__ __forceinline__ unsigned long long pk2(float xx, float yy, float dv) {
    int qx = __float2int_rn(xx * dv * 2097152.0f);
    int qy = __float2int_rn(yy * dv * 2097152.0f);
    return ((unsigned long long)(unsigned)(qx + (1 << 26)) << 32) |
           (unsigned)(qy + (1 << 26));
}

__global__ void scatter_pk_kernel(const int* __restrict__ idx, int E,
                                  const float2* __restrict__ x2,
                                  const int* __restrict__ deg,
                                  unsigned long long* __restrict__ aggP) {
    int e = (blockIdx.x * blockDim.x + threadIdx.x) * 4;
    if (((E & 3) == 0) && e + 3 < E) {
        int4 s = *(const int4*)(idx + e);
        int4 d = *(const int4*)(idx + E + e);
        float2 v0 = x2[s.x];
        float2 v1 = x2[s.y];
        float2 v2 = x2[s.z];
        float2 v3 = x2[s.w];
        float dv0 = rsqrtf((float)deg[s.x] + 1.0f);
        float dv1 = rsqrtf((float)deg[s.y] + 1.0f);
        float dv2 = rsqrtf((float)deg[s.z] + 1.0f);
        float dv3 = rsqrtf((float)deg[s.w] + 1.0f);
        atomicAdd(&aggP[d.x], pk2(v0.x, v0.y, dv0));
        atomicAdd(&aggP[d.y], pk2(v1.x, v1.y, dv1));
        atomicAdd(&aggP[d.z], pk2(v2.x, v2.y, dv2));
        atomicAdd(&aggP[d.w], pk2(v3.x, v3.y, dv3));
    } else {
        int lim = min(e + 4, E);
        for (int k = e; k < lim; ++k) {
            int s = idx[k];
            int d = idx[E + k];
            float2 v = x2[s];
            float dv = rsqrtf((float)deg[s] + 1.0f);
            atomicAdd(&aggP[d], pk2(v.x, v.y, dv));
        }
    }
}

// ---------------- MFMA LSTM: 4-wave GATE-SPLIT, 16 nodes/block, 5 blocks/CU ----------------
// r7 structure (verified) with two counter-driven fixes:
//  (a) ubuf LDS staging (16.5 KB) replaced by a 2-deep REGISTER prefetch of the raw
//      (aggP, deg, x2) streams -- phase B consumes u(t+1) loaded a full step earlier
//      (~3000 cyc in flight), issues the t+2 load. LDS 32.7 -> 17.7 KB.
//  (b) pre[] stride 17 -> 20: write bank (16q+n+c)%32 and read bank (8q+n+c)%32,
//      both <=2-way aliasing = free (stride 17 was 4-way, 3.6e7 conflicts).
// With launch_bounds(256,5): 5 blocks/CU -> 1280 resident >= 1250 blocks -> whole
// grid in ONE generation; each SIMD holds 5 waves from independent blocks to fill
// the barrier holes. Per step: A{6 h-MFMA, own-gate sigma/tanh, pre write} BAR1
// B{gather i,f,g,o; c/h update; write h; unpack prefetched u; xg(t+1); write xg;
// issue prefetch} BAR2 C{6 x-MFMA -> aX(t+1)}.

__device__ __forceinline__ float sigm_f(float x) {
    return __builtin_amdgcn_rcpf(1.0f + __expf(-x));
}
__device__ __forceinline__ float tanh_f(float x) {
    return fmaf(__builtin_amdgcn_rcpf(1.0f + __expf(-2.0f * x)), 2.0f, -1.0f);
}
// truncation split: f = hi + lo (~2^-16 rel); 3-term MFMA keeps fp32-like precision
__device__ __forceinline__ void fsplit(float f, short& hi, short& lo) {
    unsigned u = __float_as_uint(f);
    hi = (short)(u >> 16);
    float r = f - __uint_as_float(u & 0xFFFF0000u);
    lo = (short)(__float_as_uint(r) >> 16);
}
__device__ __forceinline__ int pks(short a, short b) {
    return (int)(((unsigned)(unsigned short)b << 16) | (unsigned short)a);
}

__global__ __launch_bounds__(TPB, 5) void lstm_gs2_kernel(
    const float2* __restrict__ x2,
    const unsigned long long* __restrict__ aggP, const int* __restrict__ deg,
    int N,
    const float* __restrict__ gcn_W, const float* __restrict__ gcn_b,
    const float* __restrict__ w_ih, const float* __restrict__ w_hh,
    const float* __restrict__ b_ih, const float* __restrict__ b_hh,
    const float* __restrict__ fc_W, const float* __restrict__ fc_b,
    float* __restrict__ out) {
    __shared__ float pre[4][32][PS];                  // 10.2 KB activated gates [g][u][n]
    __shared__ __align__(16) short hhb[16][XS];       // h hi  [node][unit]
    __shared__ __align__(16) short hlb[16][XS];       // h lo
    __shared__ __align__(16) short xgb[16][XS];       // xg hi
    __shared__ __align__(16) short xlb[16][XS];       // xg lo
    __shared__ float fcp[4][16];

    const int tid = threadIdx.x;
    const int w = tid >> 6;        // wave id == gate id
    const int lane = tid & 63;
    const int n = lane & 15;       // node (and A-row index in frag loads)
    const int q = lane >> 4;       // k-slice / C-row-group
    const int base = blockIdx.x * 16;

    // per-lane stream pointers for node nd (clamped; out-write guarded later)
    const int nd = min(base + n, N - 1);
    const unsigned long long* apb = aggP + (size_t)nd * SEQ;
    const int* dgb = deg + (size_t)nd * SEQ;
    const float2* xpb = x2 + (size_t)nd * SEQ;

    // ---- A-frags for gate w, tiles t1 (identity rows), hi/lo bf16 split ----
    short8 AiH[2], AiL[2], AhH[2], AhL[2];
    floatx4 biasC[2];
    #pragma unroll
    for (int t1 = 0; t1 < 2; ++t1) {
        const int arow = w * 32 + 16 * t1 + n;      // A-frag row index = lane&15
        const float* wi = w_ih + arow * HID + 8 * q;
        const float* wh = w_hh + arow * HID + 8 * q;
        #pragma unroll
        for (int j = 0; j < 8; ++j) {
            short h16, l16;
            fsplit(wi[j], h16, l16); AiH[t1][j] = h16; AiL[t1][j] = l16;
            fsplit(wh[j], h16, l16); AhH[t1][j] = h16; AhL[t1][j] = l16;
        }
        #pragma unroll
        for (int r = 0; r < 4; ++r) {
            const int brow = w * 32 + 16 * t1 + 4 * q + r;  // C row = 4q+r
            biasC[t1][r] = b_ih[brow] + b_hh[brow];
        }
    }

    // ---- owned units for act/h/xg: ua, ua+1 (ua = 8w+2q -> conflict-free LDS) ----
    const int ua = 8 * w + 2 * q;
    const float wg0a = gcn_W[ua],       wg0b = gcn_W[ua + 1];
    const float wg1a = gcn_W[HID + ua], wg1b = gcn_W[HID + ua + 1];
    const float gbca = gcn_b[ua],       gbcb = gcn_b[ua + 1];
    const float fcwa = fc_W[ua],        fcwb = fc_W[ua + 1];

    float c0 = 0.f, c1 = 0.f, ho0 = 0.f, ho1 = 0.f;

    // ---- prologue: u(0) -> xg(0); h(-1)=0 ----
    {
        int d0 = dgb[0];
        unsigned long long a0 = apb[0];
        float2 xx0 = xpb[0];
        float dv = rsqrtf((float)d0 + 1.0f);
        unsigned bias = (unsigned)d0 * 67108864u;  // deg * 2^26
        float ax = (float)((int)((unsigned)(a0 >> 32) - bias)) * (1.0f / 2097152.0f);
        float ay = (float)((int)((unsigned)a0 - bias)) * (1.0f / 2097152.0f);
        float ux = dv * fmaf(xx0.x, dv, ax);
        float uy = dv * fmaf(xx0.y, dv, ay);
        float ga = fmaxf(fmaf(ux, wg0a, fmaf(uy, wg1a, gbca)), 0.f);
        float gb = fmaxf(fmaf(ux, wg0b, fmaf(uy, wg1b, gbcb)), 0.f);
        short gah, gal, gbh, gbl;
        fsplit(ga, gah, gal); fsplit(gb, gbh, gbl);
        *(int*)&xgb[n][ua] = pks(gah, gbh);
        *(int*)&xlb[n][ua] = pks(gal, gbl);
    }
    *(int*)&hhb[n][ua] = 0;
    *(int*)&hlb[n][ua] = 0;

    // ---- prefetch u(1) into registers (consumed in phase B of t=0) ----
    unsigned long long pa = apb[1];
    int pd = dgb[1];
    float2 px = xpb[1];

    __syncthreads();

    // ---- aX(0) = bias + Wi.xg(0) ----
    floatx4 aX[2];
    {
        const short8 xh = *(const short8*)&xgb[n][8 * q];
        const short8 xl = *(const short8*)&xlb[n][8 * q];
        __builtin_amdgcn_s_setprio(1);
        #pragma unroll
        for (int t1 = 0; t1 < 2; ++t1)
            aX[t1] = __builtin_amdgcn_mfma_f32_16x16x32_bf16(AiH[t1], xh, biasC[t1], 0, 0, 0);
        #pragma unroll
        for (int t1 = 0; t1 < 2; ++t1)
            aX[t1] = __builtin_amdgcn_mfma_f32_16x16x32_bf16(AiL[t1], xh, aX[t1], 0, 0, 0);
        #pragma unroll
        for (int t1 = 0; t1 < 2; ++t1)
            aX[t1] = __builtin_amdgcn_mfma_f32_16x16x32_bf16(AiH[t1], xl, aX[t1], 0, 0, 0);
        __builtin_amdgcn_s_setprio(0);
    }

    #pragma unroll 1
    for (int t = 0; t < SEQ; ++t) {
        // ---- phase A: h-path MFMAs + own-gate nonlinearity + pre write ----
        {
            const short8 hh = *(const short8*)&hhb[n][8 * q];
            const short8 hl = *(const short8*)&hlb[n][8 * q];
            floatx4 acc[2];
            __builtin_amdgcn_s_setprio(1);
            #pragma unroll
            for (int t1 = 0; t1 < 2; ++t1)
                acc[t1] = __builtin_amdgcn_mfma_f32_16x16x32_bf16(AhH[t1], hh, aX[t1], 0, 0, 0);
            #pragma unroll
            for (int t1 = 0; t1 < 2; ++t1)
                acc[t1] = __builtin_amdgcn_mfma_f32_16x16x32_bf16(AhL[t1], hh, acc[t1], 0, 0, 0);
            #pragma unroll
            for (int t1 = 0; t1 < 2; ++t1)
                acc[t1] = __builtin_amdgcn_mfma_f32_16x16x32_bf16(AhH[t1], hl, acc[t1], 0, 0, 0);
            __builtin_amdgcn_s_setprio(0);
            float av[8];
            #pragma unroll
            for (int t1 = 0; t1 < 2; ++t1)
                #pragma unroll
                for (int r = 0; r < 4; ++r) av[4 * t1 + r] = acc[t1][r];
            if (w == 2) {   // gate g~ -> tanh; wave-uniform branch
                #pragma unroll
                for (int k = 0; k < 8; ++k) av[k] = tanh_f(av[k]);
            } else {        // gates i,f,o -> sigmoid
                #pragma unroll
                for (int k = 0; k < 8; ++k) av[k] = sigm_f(av[k]);
            }
            #pragma unroll
            for (int t1 = 0; t1 < 2; ++t1)
                #pragma unroll
                for (int r = 0; r < 4; ++r)
                    pre[w][16 * t1 + 4 * q + r][n] = av[4 * t1 + r];
        }
        __syncthreads();   // BAR1: pre complete

        // ---- phase B: gather gates; c/h update; write h; xg(t+1) from prefetch ----
        {
            const float i0 = pre[0][ua][n],     f0 = pre[1][ua][n];
            const float g0 = pre[2][ua][n],     o0 = pre[3][ua][n];
            const float i1 = pre[0][ua + 1][n], f1 = pre[1][ua + 1][n];
            const float g1 = pre[2][ua + 1][n], o1 = pre[3][ua + 1][n];
            c0 = fmaf(f0, c0, i0 * g0);
            c1 = fmaf(f1, c1, i1 * g1);
            const float h0 = o0 * tanh_f(c0);
            const float h1 = o1 * tanh_f(c1);
            ho0 = h0; ho1 = h1;
            short h0h, h0l, h1h, h1l;
            fsplit(h0, h0h, h0l); fsplit(h1, h1h, h1l);
            *(int*)&hhb[n][ua] = pks(h0h, h1h);
            *(int*)&hlb[n][ua] = pks(h0l, h1l);
            // consume prefetched u(t+1) -> xg(t+1)
            float dv = rsqrtf((float)pd + 1.0f);
            unsigned bias = (unsigned)pd * 67108864u;
            float ax = (float)((int)((unsigned)(pa >> 32) - bias)) * (1.0f / 2097152.0f);
            float ay = (float)((int)((unsigned)pa - bias)) * (1.0f / 2097152.0f);
            float ux = dv * fmaf(px.x, dv, ax);
            float uy = dv * fmaf(px.y, dv, ay);
            float ga = fmaxf(fmaf(ux, wg0a, fmaf(uy, wg1a, gbca)), 0.f);
            float gb = fmaxf(fmaf(ux, wg0b, fmaf(uy, wg1b, gbcb)), 0.f);
            short gah, gal, gbh, gbl;
            fsplit(ga, gah, gal); fsplit(gb, gbh, gbl);
            *(int*)&xgb[n][ua] = pks(gah, gbh);
            *(int*)&xlb[n][ua] = pks(gal, gbl);
            // issue prefetch for t+2 (clamped; t=127's xg(128) computed but unused)
            const int tt = min(t + 2, SEQ - 1);
            pa = apb[tt];
            pd = dgb[tt];
            px = xpb[tt];
        }
        __syncthreads();   // BAR2: h + xg complete

        // ---- phase C: aX(t+1) = bias + Wi.xg(t+1) ----
        {
            const short8 xh = *(const short8*)&xgb[n][8 * q];
            const short8 xl = *(const short8*)&xlb[n][8 * q];
            __builtin_amdgcn_s_setprio(1);
            #pragma unroll
            for (int t1 = 0; t1 < 2; ++t1)
                aX[t1] = __builtin_amdgcn_mfma_f32_16x16x32_bf16(AiH[t1], xh, biasC[t1], 0, 0, 0);
            #pragma unroll
            for (int t1 = 0; t1 < 2; ++t1)
                aX[t1] = __builtin_amdgcn_mfma_f32_16x16x32_bf16(AiL[t1], xh, aX[t1], 0, 0, 0);
            #pragma unroll
            for (int t1 = 0; t1 < 2; ++t1)
                aX[t1] = __builtin_amdgcn_mfma_f32_16x16x32_bf16(AiH[t1], xl, aX[t1], 0, 0, 0);
            __builtin_amdgcn_s_setprio(0);
        }
    }

    // ---- FC epilogue: 2 owned units, reduce over q (shfl) then waves (LDS) ----
    float partial = fmaf(ho0, fcwa, ho1 * fcwb);
    partial += __shfl_xor(partial, 16);
    partial += __shfl_xor(partial, 32);
    if (lane < 16) fcp[w][lane] = partial;
    __syncthreads();
    if (w == 0 && lane < 16) {
        const int node = base + lane;
        if (node < N)
            out[node] = fcp[0][lane] + fcp[1][lane] + fcp[2][lane] + fcp[3][lane] + fc_b[0];
    }
}

extern "C" void kernel_launch(void* const* d_in, const int* in_sizes, int n_in,
                              void* d_out, int out_size, void* d_ws, size_t ws_size,
                              hipStream_t stream) {
    const float* x     = (const float*)d_in[0];
    const int*   idx   = (const int*)d_in[1];
    const float* gcn_W = (const float*)d_in[2];
    const float* gcn_b = (const float*)d_in[3];
    const float* w_ih  = (const float*)d_in[4];
    const float* w_hh  = (const float*)d_in[5];
    const float* b_ih  = (const float*)d_in[6];
    const float* b_hh  = (const float*)d_in[7];
    const float* fc_W  = (const float*)d_in[8];
    const float* fc_b  = (const float*)d_in[9];

    const int num_nodes = in_sizes[0] / (SEQ * 2);
    const int ntot = num_nodes * SEQ;
    const int E = in_sizes[1] / 2;

    // workspace: deg[ntot i32] | aggP[ntot u64]  (3 planes of 4B)
    int* deg = (int*)d_ws;
    unsigned long long* aggP = (unsigned long long*)((char*)d_ws + (size_t)ntot * 4);

    hipMemsetAsync(d_ws, 0, (size_t)ntot * 12, stream);

    const int eb = (E + 1023) / 1024;  // 4 edges/thread, 256 threads/block
    count_kernel<<<eb, 256, 0, stream>>>(idx, E, deg);
    scatter_pk_kernel<<<eb, 256, 0, stream>>>(idx, E, (const float2*)x, deg, aggP);
    lstm_gs2_kernel<<<(num_nodes + 15) / 16, TPB, 0, stream>>>(
        (const float2*)x, aggP, deg, num_nodes,
        gcn_W, gcn_b, w_ih, w_hh, b_ih, b_hh, fc_W, fc_b,
        (float*)d_out);
}

// Round 9
// 476.355 us; speedup vs baseline: 1.0812x; 1.0812x over previous
//
#include <hip/hip_runtime.h>

#define SEQ 128
#define HID 32
#define TPB 256   // 4 waves, 16 nodes per block, gate-split across waves
#define XS 40     // LDS row stride in shorts: 80B = 5*16B (16B-aligned b128 rows)

typedef __attribute__((ext_vector_type(8))) short short8;   // 8 bf16 = 4 VGPR
typedef __attribute__((ext_vector_type(4))) float floatx4;  // MFMA acc

// ---------------- GCN prep (identical to round-5 verified version) ----------------

__global__ void count_kernel(const int* __restrict__ idx, int E, int* __restrict__ cnt) {
    int e = (blockIdx.x * blockDim.x + threadIdx.x) * 4;
    if (((E & 3) == 0) && e + 3 < E) {
        int4 d = *(const int4*)(idx + E + e);   // 16B aligned: E%4==0, e%4==0
        atomicAdd(&cnt[d.x], 1);
        atomicAdd(&cnt[d.y], 1);
        atomicAdd(&cnt[d.z], 1);
        atomicAdd(&cnt[d.w], 1);
    } else {
        int lim = min(e + 4, E);
        for (int k = e; k < lim; ++k) atomicAdd(&cnt[idx[E + k]], 1);
    }
}

// Fixed-point pack: q = rn(v * 2^21), biased +2^26 per 32b field -> every added term
// positive and < 2^26.2, no cross-field carry up to ~56 adds. ONE u64 atomic per
// edge; dinv[src] computed inline from the deg gather (scatter is atomic-rate-bound).
__device__ __forceinline__ unsigned long long pk2(float xx, float yy, float dv) {
    int qx = __float2int_rn(xx * dv * 2097152.0f);
    int qy = __float2int_rn(yy * dv * 2097152.0f);
    return ((unsigned long long)(unsigned)(qx + (1 << 26)) << 32) |
           (unsigned)(qy + (1 << 26));
}

__global__ void scatter_pk_kernel(const int* __restrict__ idx, int E,
                                  const float2* __restrict__ x2,
                                  const int* __restrict__ deg,
                                  unsigned long long* __restrict__ aggP) {
    int e = (blockIdx.x * blockDim.x + threadIdx.x) * 4;
    if (((E & 3) == 0) && e + 3 < E) {
        int4 s = *(const int4*)(idx + e);
        int4 d = *(const int4*)(idx + E + e);
        float2 v0 = x2[s.x];
        float2 v1 = x2[s.y];
        float2 v2 = x2[s.z];
        float2 v3 = x2[s.w];
        float dv0 = rsqrtf((float)deg[s.x] + 1.0f);
        float dv1 = rsqrtf((float)deg[s.y] + 1.0f);
        float dv2 = rsqrtf((float)deg[s.z] + 1.0f);
        float dv3 = rsqrtf((float)deg[s.w] + 1.0f);
        atomicAdd(&aggP[d.x], pk2(v0.x, v0.y, dv0));
        atomicAdd(&aggP[d.y], pk2(v1.x, v1.y, dv1));
        atomicAdd(&aggP[d.z], pk2(v2.x, v2.y, dv2));
        atomicAdd(&aggP[d.w], pk2(v3.x, v3.y, dv3));
    } else {
        int lim = min(e + 4, E);
        for (int k = e; k < lim; ++k) {
            int s = idx[k];
            int d = idx[E + k];
            float2 v = x2[s];
            float dv = rsqrtf((float)deg[s] + 1.0f);
            atomicAdd(&aggP[d], pk2(v.x, v.y, dv));
        }
    }
}

// ---------------- MFMA LSTM: 4-wave GATE-SPLIT, 16 nodes/block ----------------
// r7 structure (verified correct) + three counter-driven fixes:
//  (a) LDS 32.7 -> 30.6 KB (XS 56->40; pre re-layout) -> 5 blocks/CU resident ->
//      all 1250 blocks in ONE generation (r7 LDS=32768 risked a 2-gen tail).
//      ubuf STAYS in LDS -- r8's register prefetch spilled (WRITE_SIZE 78KB->35MB).
//  (b) pre[32][4][17] (unit-major): write bank (16q+n+c)%32, read bank (8q+n+c)%32,
//      both exactly 2-way = free (r7's [4][32][17] was 4-way on all 16 ops/step).
//  (c) VALU diet: log2e (i,f,o) / 2*log2e (g~) folded into Wi/Wh/bias at frag load
//      -> act = rcp(1+exp2(-y)), negate is a free VOP3 input modifier (-8 mul/step);
//      hi/lo pair-split via v_perm_b32 (fsplit2: 6 ops vs 10) on h-pair and xg-pair.
// Per step: A{6 h-MFMA, own-gate act, pre write} BAR1 B{gather i,f,g,o; c/h update;
// write h; xg(t+1) from ubuf; write xg} BAR2 C{6 x-MFMA -> aX(t+1)}.

__device__ __forceinline__ float tanh_f(float x) {
    return fmaf(__builtin_amdgcn_rcpf(1.0f + __expf(-2.0f * x)), 2.0f, -1.0f);
}
// truncation split: f = hi + lo (~2^-16 rel); 3-term MFMA keeps fp32-like precision
__device__ __forceinline__ void fsplit(float f, short& hi, short& lo) {
    unsigned u = __float_as_uint(f);
    hi = (short)(u >> 16);
    float r = f - __uint_as_float(u & 0xFFFF0000u);
    lo = (short)(__float_as_uint(r) >> 16);
}
// pair split: hi word = (hi16(b)<<16)|hi16(a), lo word likewise, via v_perm_b32
__device__ __forceinline__ void fsplit2(float a, float b, unsigned& hi, unsigned& lo) {
    unsigned ta = __float_as_uint(a) & 0xFFFF0000u;
    unsigned tb = __float_as_uint(b) & 0xFFFF0000u;
    float ra = a - __uint_as_float(ta);
    float rb = b - __uint_as_float(tb);
    hi = __builtin_amdgcn_perm(__float_as_uint(b), __float_as_uint(a), 0x07060302u);
    lo = __builtin_amdgcn_perm(__float_as_uint(rb), __float_as_uint(ra), 0x07060302u);
}

__global__ __launch_bounds__(TPB, 4) void lstm_gs3_kernel(
    const float2* __restrict__ x2,
    const unsigned long long* __restrict__ aggP, const int* __restrict__ deg,
    int N,
    const float* __restrict__ gcn_W, const float* __restrict__ gcn_b,
    const float* __restrict__ w_ih, const float* __restrict__ w_hh,
    const float* __restrict__ b_ih, const float* __restrict__ b_hh,
    const float* __restrict__ fc_W, const float* __restrict__ fc_b,
    float* __restrict__ out) {
    __shared__ float2 ubuf[16][SEQ + 1];              // 16.5 KB; col 128 = zero pad
    __shared__ float pre[32][4][17];                  // 8.7 KB activated gates [u][g][n]
    __shared__ __align__(16) short hhb[16][XS];       // h hi  [node][unit]
    __shared__ __align__(16) short hlb[16][XS];       // h lo
    __shared__ __align__(16) short xgb[16][XS];       // xg hi
    __shared__ __align__(16) short xlb[16][XS];       // xg lo
    __shared__ float fcp[4][16];

    const int tid = threadIdx.x;
    const int w = tid >> 6;        // wave id == gate id
    const int lane = tid & 63;
    const int n = lane & 15;       // node (and A-row index in frag loads)
    const int q = lane >> 4;       // k-slice / C-row-group
    const int base = blockIdx.x * 16;

    // ---- stage u[node][t] = dv*(agg + x*dv) into LDS (coalesced, 8 iters) ----
    {
        const float2* xb = x2 + (size_t)base * SEQ;
        const unsigned long long* apb = aggP + (size_t)base * SEQ;
        const int* dgb = deg + (size_t)base * SEQ;
        const int lim = min(16 * SEQ, (N - base) * SEQ);
        for (int i = tid; i < 16 * SEQ; i += TPB) {
            float2 v = make_float2(0.f, 0.f);
            if (i < lim) {
                int dg = dgb[i];
                float dv = rsqrtf((float)dg + 1.0f);
                float2 xx = xb[i];
                unsigned long long pk = apb[i];
                unsigned bias = (unsigned)dg * 67108864u;  // deg * 2^26
                float ax = (float)((int)((unsigned)(pk >> 32) - bias)) * (1.0f / 2097152.0f);
                float ay = (float)((int)((unsigned)pk - bias)) * (1.0f / 2097152.0f);
                v = make_float2(dv * fmaf(xx.x, dv, ax), dv * fmaf(xx.y, dv, ay));
            }
            ubuf[i >> 7][i & 127] = v;
        }
        if (tid < 16) ubuf[tid][SEQ] = make_float2(0.f, 0.f);
    }

    // ---- A-frags for gate w (identity rows), hi/lo bf16, exp2-scale folded ----
    // gates i,f,o: scale log2(e); gate g~ (w==2): 2*log2(e). Then activation is
    // rcp(1+exp2(-y)) (sigmoid) or fma(rcp(1+exp2(-y)),2,-1) (tanh).
    const float gsc = (w == 2) ? 2.8853900817779268f : 1.4426950408889634f;
    short8 AiH[2], AiL[2], AhH[2], AhL[2];
    floatx4 biasC[2];
    #pragma unroll
    for (int t1 = 0; t1 < 2; ++t1) {
        const int arow = w * 32 + 16 * t1 + n;      // A-frag row index = lane&15
        const float* wi = w_ih + arow * HID + 8 * q;
        const float* wh = w_hh + arow * HID + 8 * q;
        #pragma unroll
        for (int j = 0; j < 8; ++j) {
            short h16, l16;
            fsplit(wi[j] * gsc, h16, l16); AiH[t1][j] = h16; AiL[t1][j] = l16;
            fsplit(wh[j] * gsc, h16, l16); AhH[t1][j] = h16; AhL[t1][j] = l16;
        }
        #pragma unroll
        for (int r = 0; r < 4; ++r) {
            const int brow = w * 32 + 16 * t1 + 4 * q + r;  // C row = 4q+r
            biasC[t1][r] = (b_ih[brow] + b_hh[brow]) * gsc;
        }
    }

    // ---- owned units for act/h/xg: ua, ua+1 (ua = 8w+2q -> conflict-free LDS) ----
    const int ua = 8 * w + 2 * q;
    const float wg0a = gcn_W[ua],       wg0b = gcn_W[ua + 1];
    const float wg1a = gcn_W[HID + ua], wg1b = gcn_W[HID + ua + 1];
    const float gbca = gcn_b[ua],       gbcb = gcn_b[ua + 1];
    const float fcwa = fc_W[ua],        fcwb = fc_W[ua + 1];

    float c0 = 0.f, c1 = 0.f, ho0 = 0.f, ho1 = 0.f;

    __syncthreads();   // ubuf staged

    // ---- prologue: h(-1)=0 and xg(0) ----
    *(int*)&hhb[n][ua] = 0;
    *(int*)&hlb[n][ua] = 0;
    {
        float2 uu = ubuf[n][0];
        float ga = fmaxf(fmaf(uu.x, wg0a, fmaf(uu.y, wg1a, gbca)), 0.f);
        float gb = fmaxf(fmaf(uu.x, wg0b, fmaf(uu.y, wg1b, gbcb)), 0.f);
        unsigned hi, lo;
        fsplit2(ga, gb, hi, lo);
        *(unsigned*)&xgb[n][ua] = hi;
        *(unsigned*)&xlb[n][ua] = lo;
    }
    __syncthreads();

    // ---- aX(0) = bias + Wi.xg(0) ----
    floatx4 aX[2];
    {
        const short8 xh = *(const short8*)&xgb[n][8 * q];
        const short8 xl = *(const short8*)&xlb[n][8 * q];
        __builtin_amdgcn_s_setprio(1);
        #pragma unroll
        for (int t1 = 0; t1 < 2; ++t1)
            aX[t1] = __builtin_amdgcn_mfma_f32_16x16x32_bf16(AiH[t1], xh, biasC[t1], 0, 0, 0);
        #pragma unroll
        for (int t1 = 0; t1 < 2; ++t1)
            aX[t1] = __builtin_amdgcn_mfma_f32_16x16x32_bf16(AiL[t1], xh, aX[t1], 0, 0, 0);
        #pragma unroll
        for (int t1 = 0; t1 < 2; ++t1)
            aX[t1] = __builtin_amdgcn_mfma_f32_16x16x32_bf16(AiH[t1], xl, aX[t1], 0, 0, 0);
        __builtin_amdgcn_s_setprio(0);
    }

    #pragma unroll 1
    for (int t = 0; t < SEQ; ++t) {
        // ---- phase A: h-path MFMAs + own-gate activation + pre write ----
        {
            const short8 hh = *(const short8*)&hhb[n][8 * q];
            const short8 hl = *(const short8*)&hlb[n][8 * q];
            floatx4 acc[2];
            __builtin_amdgcn_s_setprio(1);
            #pragma unroll
            for (int t1 = 0; t1 < 2; ++t1)
                acc[t1] = __builtin_amdgcn_mfma_f32_16x16x32_bf16(AhH[t1], hh, aX[t1], 0, 0, 0);
            #pragma unroll
            for (int t1 = 0; t1 < 2; ++t1)
                acc[t1] = __builtin_amdgcn_mfma_f32_16x16x32_bf16(AhL[t1], hh, acc[t1], 0, 0, 0);
            #pragma unroll
            for (int t1 = 0; t1 < 2; ++t1)
                acc[t1] = __builtin_amdgcn_mfma_f32_16x16x32_bf16(AhH[t1], hl, acc[t1], 0, 0, 0);
            __builtin_amdgcn_s_setprio(0);
            #pragma unroll
            for (int t1 = 0; t1 < 2; ++t1) {
                #pragma unroll
                for (int r = 0; r < 4; ++r) {
                    const float y = acc[t1][r];
                    const float e = __builtin_amdgcn_exp2f(-y);
                    const float s = __builtin_amdgcn_rcpf(1.0f + e);
                    const float av = (w == 2) ? fmaf(s, 2.0f, -1.0f) : s;  // wave-uniform
                    pre[16 * t1 + 4 * q + r][w][n] = av;
                }
            }
        }
        __syncthreads();   // BAR1: pre complete

        // ---- phase B: gather gates; c/h update; write h; xg(t+1) from ubuf ----
        {
            const float i0 = pre[ua][0][n],     f0 = pre[ua][1][n];
            const float g0 = pre[ua][2][n],     o0 = pre[ua][3][n];
            const float i1 = pre[ua + 1][0][n], f1 = pre[ua + 1][1][n];
            const float g1 = pre[ua + 1][2][n], o1 = pre[ua + 1][3][n];
            c0 = fmaf(f0, c0, i0 * g0);
            c1 = fmaf(f1, c1, i1 * g1);
            const float h0 = o0 * tanh_f(c0);
            const float h1 = o1 * tanh_f(c1);
            ho0 = h0; ho1 = h1;
            unsigned hi, lo;
            fsplit2(h0, h1, hi, lo);
            *(unsigned*)&hhb[n][ua] = hi;
            *(unsigned*)&hlb[n][ua] = lo;
            // xg(t+1): t=127 reads zero pad col; result never consumed
            float2 uu = ubuf[n][t + 1];
            float ga = fmaxf(fmaf(uu.x, wg0a, fmaf(uu.y, wg1a, gbca)), 0.f);
            float gb = fmaxf(fmaf(uu.x, wg0b, fmaf(uu.y, wg1b, gbcb)), 0.f);
            fsplit2(ga, gb, hi, lo);
            *(unsigned*)&xgb[n][ua] = hi;
            *(unsigned*)&xlb[n][ua] = lo;
        }
        __syncthreads();   // BAR2: h + xg complete

        // ---- phase C: aX(t+1) = bias + Wi.xg(t+1) ----
        {
            const short8 xh = *(const short8*)&xgb[n][8 * q];
            const short8 xl = *(const short8*)&xlb[n][8 * q];
            __builtin_amdgcn_s_setprio(1);
            #pragma unroll
            for (int t1 = 0; t1 < 2; ++t1)
                aX[t1] = __builtin_amdgcn_mfma_f32_16x16x32_bf16(AiH[t1], xh, biasC[t1], 0, 0, 0);
            #pragma unroll
            for (int t1 = 0; t1 < 2; ++t1)
                aX[t1] = __builtin_amdgcn_mfma_f32_16x16x32_bf16(AiL[t1], xh, aX[t1], 0, 0, 0);
            #pragma unroll
            for (int t1 = 0; t1 < 2; ++t1)
                aX[t1] = __builtin_amdgcn_mfma_f32_16x16x32_bf16(AiH[t1], xl, aX[t1], 0, 0, 0);
            __builtin_amdgcn_s_setprio(0);
        }
    }

    // ---- FC epilogue: 2 owned units, reduce over q (shfl) then waves (LDS) ----
    float partial = fmaf(ho0, fcwa, ho1 * fcwb);
    partial += __shfl_xor(partial, 16);
    partial += __shfl_xor(partial, 32);
    if (lane < 16) fcp[w][lane] = partial;
    __syncthreads();
    if (w == 0 && lane < 16) {
        const int node = base + lane;
        if (node < N)
            out[node] = fcp[0][lane] + fcp[1][lane] + fcp[2][lane] + fcp[3][lane] + fc_b[0];
    }
}

extern "C" void kernel_launch(void* const* d_in, const int* in_sizes, int n_in,
                              void* d_out, int out_size, void* d_ws, size_t ws_size,
                              hipStream_t stream) {
    const float* x     = (const float*)d_in[0];
    const int*   idx   = (const int*)d_in[1];
    const float* gcn_W = (const float*)d_in[2];
    const float* gcn_b = (const float*)d_in[3];
    const float* w_ih  = (const float*)d_in[4];
    const float* w_hh  = (const float*)d_in[5];
    const float* b_ih  = (const float*)d_in[6];
    const float* b_hh  = (const float*)d_in[7];
    const float* fc_W  = (const float*)d_in[8];
    const float* fc_b  = (const float*)d_in[9];

    const int num_nodes = in_sizes[0] / (SEQ * 2);
    const int ntot = num_nodes * SEQ;
    const int E = in_sizes[1] / 2;

    // workspace: deg[ntot i32] | aggP[ntot u64]  (3 planes of 4B)
    int* deg = (int*)d_ws;
    unsigned long long* aggP = (unsigned long long*)((char*)d_ws + (size_t)ntot * 4);

    hipMemsetAsync(d_ws, 0, (size_t)ntot * 12, stream);

    const int eb = (E + 1023) / 1024;  // 4 edges/thread, 256 threads/block
    count_kernel<<<eb, 256, 0, stream>>>(idx, E, deg);
    scatter_pk_kernel<<<eb, 256, 0, stream>>>(idx, E, (const float2*)x, deg, aggP);
    lstm_gs3_kernel<<<(num_nodes + 15) / 16, TPB, 0, stream>>>(
        (const float2*)x, aggP, deg, num_nodes,
        gcn_W, gcn_b, w_ih, w_hh, b_ih, b_hh, fc_W, fc_b,
        (float*)d_out);
}

// Round 10
// 471.587 us; speedup vs baseline: 1.0921x; 1.0101x over previous
//
#include <hip/hip_runtime.h>

#define SEQ 128
#define HID 32
#define TPB2 128  // 2 waves, 16 nodes per block; wave = unit-half (t1)
#define XS 40     // LDS row stride in shorts: 80B = 5*16B (16B-aligned b128 rows)

typedef __attribute__((ext_vector_type(8))) short short8;   // 8 bf16 = 4 VGPR
typedef __attribute__((ext_vector_type(4))) float floatx4;  // MFMA acc

// ---------------- GCN prep (identical to round-9 verified version) ----------------

__global__ void count_kernel(const int* __restrict__ idx, int E, int* __restrict__ cnt) {
    int e = (blockIdx.x * blockDim.x + threadIdx.x) * 4;
    if (((E & 3) == 0) && e + 3 < E) {
        int4 d = *(const int4*)(idx + E + e);   // 16B aligned: E%4==0, e%4==0
        atomicAdd(&cnt[d.x], 1);
        atomicAdd(&cnt[d.y], 1);
        atomicAdd(&cnt[d.z], 1);
        atomicAdd(&cnt[d.w], 1);
    } else {
        int lim = min(e + 4, E);
        for (int k = e; k < lim; ++k) atomicAdd(&cnt[idx[E + k]], 1);
    }
}

// Fixed-point pack: q = rn(v * 2^21), biased +2^26 per 32b field -> every added term
// positive and < 2^26.2, no cross-field carry up to ~56 adds. ONE u64 atomic per
// edge; dinv[src] computed inline from the deg gather (scatter is atomic-rate-bound).
__device__ __forceinline__ unsigned long long pk2(float xx, float yy, float dv) {
    int qx = __float2int_rn(xx * dv * 2097152.0f);
    int qy = __float2int_rn(yy * dv * 2097152.0f);
    return ((unsigned long long)(unsigned)(qx + (1 << 26)) << 32) |
           (unsigned)(qy + (1 << 26));
}

__global__ void scatter_pk_kernel(const int* __restrict__ idx, int E,
                                  const float2* __restrict__ x2,
                                  const int* __restrict__ deg,
                                  unsigned long long* __restrict__ aggP) {
    int e = (blockIdx.x * blockDim.x + threadIdx.x) * 4;
    if (((E & 3) == 0) && e + 3 < E) {
        int4 s = *(const int4*)(idx + e);
        int4 d = *(const int4*)(idx + E + e);
        float2 v0 = x2[s.x];
        float2 v1 = x2[s.y];
        float2 v2 = x2[s.z];
        float2 v3 = x2[s.w];
        float dv0 = rsqrtf((float)deg[s.x] + 1.0f);
        float dv1 = rsqrtf((float)deg[s.y] + 1.0f);
        float dv2 = rsqrtf((float)deg[s.z] + 1.0f);
        float dv3 = rsqrtf((float)deg[s.w] + 1.0f);
        atomicAdd(&aggP[d.x], pk2(v0.x, v0.y, dv0));
        atomicAdd(&aggP[d.y], pk2(v1.x, v1.y, dv1));
        atomicAdd(&aggP[d.z], pk2(v2.x, v2.y, dv2));
        atomicAdd(&aggP[d.w], pk2(v3.x, v3.y, dv3));
    } else {
        int lim = min(e + 4, E);
        for (int k = e; k < lim; ++k) {
            int s = idx[k];
            int d = idx[E + k];
            float2 v = x2[s];
            float dv = rsqrtf((float)deg[s] + 1.0f);
            atomicAdd(&aggP[d], pk2(v.x, v.y, dv));
        }
    }
}

// -------- MFMA LSTM: OPERAND-SWAPPED gates^T = [x;h].W^T, lane-local cell --------
// mfma(A=x/h frag, B=W frag, C): A keeps the session-verified per-lane pattern
// (lane holds node l&15, k-slice 8q+j -- same LDS b128 read as all prior rounds);
// B keeps the verified identity-row weight pattern (row = g*32+16*t1+(l&15),
// elements 8q+j). C-layout (col=l&15, row=4q+r) then gives lane (u=l&15, q) the
// pre-acts of ALL FOUR gates for unit 16*t1+u, nodes 4q+r -> sigmoid/tanh,
// c-update, h ALL IN-LANE. The pre[] exchange (16 LDS ops + 1 barrier/step of
// r9) is deleted. Only h crosses waves (wave t1 writes units 16*t1..+15, reads
// all 32). ONE barrier/step; h double-buffered with compile-time parity
// (race-free: reads of buf P drain at the barrier before buf P is rewritten).
// xg A-frags computed in-lane from ubuf (dup x2 waves; independent of barrier).
// 2 waves/block, 1250 blocks; launch_bounds(128,3) caps VGPR at 170 (est ~155).

__device__ __forceinline__ float sg(float y) {       // sigmoid, exp2-prescaled input
    return __builtin_amdgcn_rcpf(1.0f + __builtin_amdgcn_exp2f(-y));
}
__device__ __forceinline__ float tanh_f(float x) {   // unscaled input
    return fmaf(__builtin_amdgcn_rcpf(1.0f + __expf(-2.0f * x)), 2.0f, -1.0f);
}
// truncation split: f = hi + lo (~2^-16 rel); 3-term MFMA keeps fp32-like precision
__device__ __forceinline__ void fsplit(float f, short& hi, short& lo) {
    unsigned u = __float_as_uint(f);
    hi = (short)(u >> 16);
    float r = f - __uint_as_float(u & 0xFFFF0000u);
    lo = (short)(__float_as_uint(r) >> 16);
}
// pair split via v_perm_b32 (verified r9): hi word = (hi16(b)<<16)|hi16(a)
__device__ __forceinline__ void fsplit2(float a, float b, unsigned& hi, unsigned& lo) {
    unsigned ta = __float_as_uint(a) & 0xFFFF0000u;
    unsigned tb = __float_as_uint(b) & 0xFFFF0000u;
    float ra = a - __uint_as_float(ta);
    float rb = b - __uint_as_float(tb);
    hi = __builtin_amdgcn_perm(__float_as_uint(b), __float_as_uint(a), 0x07060302u);
    lo = __builtin_amdgcn_perm(__float_as_uint(rb), __float_as_uint(ra), 0x07060302u);
}

__global__ __launch_bounds__(TPB2, 3) void lstm_sw2_kernel(
    const float2* __restrict__ x2,
    const unsigned long long* __restrict__ aggP, const int* __restrict__ deg,
    int N,
    const float* __restrict__ gcn_W, const float* __restrict__ gcn_b,
    const float* __restrict__ w_ih, const float* __restrict__ w_hh,
    const float* __restrict__ b_ih, const float* __restrict__ b_hh,
    const float* __restrict__ fc_W, const float* __restrict__ fc_b,
    float* __restrict__ out) {
    __shared__ float2 ubuf[16][SEQ + 1];                  // 16.5 KB; col 128 = zero pad
    __shared__ __align__(16) short hhb[2][16][XS];        // h hi [parity][node][unit]
    __shared__ __align__(16) short hlb[2][16][XS];        // h lo
    __shared__ float fcp[2][16];

    const int tid = threadIdx.x;
    const int t1 = tid >> 6;       // wave id == unit-half
    const int lane = tid & 63;
    const int n = lane & 15;       // A-row (node) / C-col (unit) / B-col (gate-row)
    const int q = lane >> 4;       // k-slice / C-row-group
    const int base = blockIdx.x * 16;

    // ---- stage u[node][t] = dv*(agg + x*dv) into LDS (coalesced, 16 iters) ----
    {
        const float2* xb = x2 + (size_t)base * SEQ;
        const unsigned long long* apb = aggP + (size_t)base * SEQ;
        const int* dgb = deg + (size_t)base * SEQ;
        const int lim = min(16 * SEQ, (N - base) * SEQ);
        for (int i = tid; i < 16 * SEQ; i += TPB2) {
            float2 v = make_float2(0.f, 0.f);
            if (i < lim) {
                int dg = dgb[i];
                float dv = rsqrtf((float)dg + 1.0f);
                float2 xx = xb[i];
                unsigned long long pk = apb[i];
                unsigned bias = (unsigned)dg * 67108864u;  // deg * 2^26
                float ax = (float)((int)((unsigned)(pk >> 32) - bias)) * (1.0f / 2097152.0f);
                float ay = (float)((int)((unsigned)pk - bias)) * (1.0f / 2097152.0f);
                v = make_float2(dv * fmaf(xx.x, dv, ax), dv * fmaf(xx.y, dv, ay));
            }
            ubuf[i >> 7][i & 127] = v;
        }
        if (tid < 16) ubuf[tid][SEQ] = make_float2(0.f, 0.f);
        // zero h parity-0 buffers (read at t=0): 320+320 dwords
        for (int i = tid; i < 320; i += TPB2) {
            ((int*)hhb[0])[i] = 0;
            ((int*)hlb[0])[i] = 0;
        }
    }

    // ---- W B-frags: 4 gate-tiles for unit-half t1, hi/lo bf16, exp2-scale folded ----
    short8 WiH[4], WiL[4], WhH[4], WhL[4];
    floatx4 biasv[4];
    #pragma unroll
    for (int g = 0; g < 4; ++g) {
        const float gsc = (g == 2) ? 2.8853900817779268f : 1.4426950408889634f;
        const int arow = g * 32 + 16 * t1 + n;   // B-frag col index = lane&15
        const float* wi = w_ih + arow * HID + 8 * q;
        const float* wh = w_hh + arow * HID + 8 * q;
        #pragma unroll
        for (int j = 0; j < 8; ++j) {
            short h16, l16;
            fsplit(wi[j] * gsc, h16, l16); WiH[g][j] = h16; WiL[g][j] = l16;
            fsplit(wh[j] * gsc, h16, l16); WhH[g][j] = h16; WhL[g][j] = l16;
        }
        const float bb = (b_ih[arow] + b_hh[arow]) * gsc;   // C-col bias: same for all rows
        biasv[g] = (floatx4){bb, bb, bb, bb};
    }

    // ---- GCN consts for the xg A-frag (units 8q..8q+7 of node n) ----
    float wg0[8], wg1[8], gbc[8];
    #pragma unroll
    for (int j = 0; j < 8; ++j) {
        const int u = 8 * q + j;
        wg0[j] = gcn_W[u];
        wg1[j] = gcn_W[HID + u];
        gbc[j] = gcn_b[u];
    }
    const float fcw = fc_W[16 * t1 + n];   // lane's output unit

    float c[4] = {0.f, 0.f, 0.f, 0.f};
    float ho[4] = {0.f, 0.f, 0.f, 0.f};

// xg A-frag for time TT: units 8q..8q+7 of node n, packed hi/lo via fsplit2
#define XG_FRAGS(TT, XH, XL)                                                      \
    {                                                                             \
        float2 uu = ubuf[n][TT];                                                  \
        float gv[8];                                                              \
        _Pragma("unroll") for (int j = 0; j < 8; ++j)                             \
            gv[j] = fmaxf(fmaf(uu.x, wg0[j], fmaf(uu.y, wg1[j], gbc[j])), 0.f);   \
        unsigned hp0, lp0, hp1, lp1, hp2, lp2, hp3, lp3;                          \
        fsplit2(gv[0], gv[1], hp0, lp0);                                          \
        fsplit2(gv[2], gv[3], hp1, lp1);                                          \
        fsplit2(gv[4], gv[5], hp2, lp2);                                          \
        fsplit2(gv[6], gv[7], hp3, lp3);                                          \
        int4 th = make_int4((int)hp0, (int)hp1, (int)hp2, (int)hp3);              \
        int4 tl = make_int4((int)lp0, (int)lp1, (int)lp2, (int)lp3);              \
        XH = *(short8*)&th;                                                       \
        XL = *(short8*)&tl;                                                       \
    }

    short8 xh, xl;
    XG_FRAGS(0, xh, xl);   // xg(0)
    __syncthreads();       // ubuf + h-zero visible

// One step, compile-time parity P: reads h(t-1) from buf P, writes h(t) to buf P^1.
// Swapped MFMA: acc = bias + xg.Wi^T + h.Wh^T (3 hi/lo terms each, width-4 ILP).
#define LSTM_STEP(P, TT)                                                                    \
    do {                                                                                    \
        const short8 hh = *(const short8*)&hhb[P][n][8 * q];                                \
        const short8 hl = *(const short8*)&hlb[P][n][8 * q];                                \
        floatx4 acc[4];                                                                     \
        __builtin_amdgcn_s_setprio(1);                                                      \
        _Pragma("unroll") for (int g = 0; g < 4; ++g)                                       \
            acc[g] = __builtin_amdgcn_mfma_f32_16x16x32_bf16(xh, WiH[g], biasv[g], 0, 0, 0); \
        _Pragma("unroll") for (int g = 0; g < 4; ++g)                                       \
            acc[g] = __builtin_amdgcn_mfma_f32_16x16x32_bf16(xh, WiL[g], acc[g], 0, 0, 0);  \
        _Pragma("unroll") for (int g = 0; g < 4; ++g)                                       \
            acc[g] = __builtin_amdgcn_mfma_f32_16x16x32_bf16(xl, WiH[g], acc[g], 0, 0, 0);  \
        _Pragma("unroll") for (int g = 0; g < 4; ++g)                                       \
            acc[g] = __builtin_amdgcn_mfma_f32_16x16x32_bf16(hh, WhH[g], acc[g], 0, 0, 0);  \
        _Pragma("unroll") for (int g = 0; g < 4; ++g)                                       \
            acc[g] = __builtin_amdgcn_mfma_f32_16x16x32_bf16(hh, WhL[g], acc[g], 0, 0, 0);  \
        _Pragma("unroll") for (int g = 0; g < 4; ++g)                                       \
            acc[g] = __builtin_amdgcn_mfma_f32_16x16x32_bf16(hl, WhH[g], acc[g], 0, 0, 0);  \
        __builtin_amdgcn_s_setprio(0);                                                      \
        XG_FRAGS((TT) + 1, xh, xl); /* next step's xg; overlaps MFMA latency */             \
        _Pragma("unroll") for (int r = 0; r < 4; ++r) {                                     \
            const float ig = sg(acc[0][r]);                                                 \
            const float fg = sg(acc[1][r]);                                                 \
            const float gg = fmaf(sg(acc[2][r]), 2.0f, -1.0f);                              \
            const float og = sg(acc[3][r]);                                                 \
            c[r] = fmaf(fg, c[r], ig * gg);                                                 \
            const float hv = og * tanh_f(c[r]);                                             \
            ho[r] = hv;                                                                     \
            short h16, l16;                                                                 \
            fsplit(hv, h16, l16);                                                           \
            hhb[(P) ^ 1][4 * q + r][16 * t1 + n] = h16;                                     \
            hlb[(P) ^ 1][4 * q + r][16 * t1 + n] = l16;                                     \
        }                                                                                   \
        __syncthreads();                                                                    \
    } while (0)

    #pragma unroll 1
    for (int t = 0; t < SEQ; t += 2) {
        LSTM_STEP(0, t);        // reads h buf 0, writes buf 1
        LSTM_STEP(1, t + 1);    // reads h buf 1, writes buf 0
    }
#undef LSTM_STEP
#undef XG_FRAGS

    // ---- FC epilogue: lane holds h(127) of unit 16t1+n, nodes 4q+r ----
    float p0 = ho[0] * fcw, p1 = ho[1] * fcw, p2 = ho[2] * fcw, p3 = ho[3] * fcw;
    #pragma unroll
    for (int m = 1; m < 16; m <<= 1) {   // reduce over the 16 unit-lanes (same q)
        p0 += __shfl_xor(p0, m);
        p1 += __shfl_xor(p1, m);
        p2 += __shfl_xor(p2, m);
        p3 += __shfl_xor(p3, m);
    }
    if (n == 0) {
        fcp[t1][4 * q + 0] = p0;
        fcp[t1][4 * q + 1] = p1;
        fcp[t1][4 * q + 2] = p2;
        fcp[t1][4 * q + 3] = p3;
    }
    __syncthreads();
    if (t1 == 0 && lane < 16) {
        const int node = base + lane;
        if (node < N) out[node] = fcp[0][lane] + fcp[1][lane] + fc_b[0];
    }
}

extern "C" void kernel_launch(void* const* d_in, const int* in_sizes, int n_in,
                              void* d_out, int out_size, void* d_ws, size_t ws_size,
                              hipStream_t stream) {
    const float* x     = (const float*)d_in[0];
    const int*   idx   = (const int*)d_in[1];
    const float* gcn_W = (const float*)d_in[2];
    const float* gcn_b = (const float*)d_in[3];
    const float* w_ih  = (const float*)d_in[4];
    const float* w_hh  = (const float*)d_in[5];
    const float* b_ih  = (const float*)d_in[6];
    const float* b_hh  = (const float*)d_in[7];
    const float* fc_W  = (const float*)d_in[8];
    const float* fc_b  = (const float*)d_in[9];

    const int num_nodes = in_sizes[0] / (SEQ * 2);
    const int ntot = num_nodes * SEQ;
    const int E = in_sizes[1] / 2;

    // workspace: deg[ntot i32] | aggP[ntot u64]  (3 planes of 4B)
    int* deg = (int*)d_ws;
    unsigned long long* aggP = (unsigned long long*)((char*)d_ws + (size_t)ntot * 4);

    hipMemsetAsync(d_ws, 0, (size_t)ntot * 12, stream);

    const int eb = (E + 1023) / 1024;  // 4 edges/thread, 256 threads/block
    count_kernel<<<eb, 256, 0, stream>>>(idx, E, deg);
    scatter_pk_kernel<<<eb, 256, 0, stream>>>(idx, E, (const float2*)x, deg, aggP);
    lstm_sw2_kernel<<<(num_nodes + 15) / 16, TPB2, 0, stream>>>(
        (const float2*)x, aggP, deg, num_nodes,
        gcn_W, gcn_b, w_ih, w_hh, b_ih, b_hh, fc_W, fc_b,
        (float*)d_out);
}

// Round 11
// 459.223 us; speedup vs baseline: 1.1216x; 1.0269x over previous
//
#include <hip/hip_runtime.h>

#define SEQ 128
#define HID 32
#define TPB2 128  // 2 waves, 16 nodes per block; wave = unit-half (t1)
#define XS 40     // LDS row stride in shorts: 80B = 5*16B (16B-aligned b128 rows)

typedef __attribute__((ext_vector_type(8))) short short8;   // 8 bf16 = 4 VGPR
typedef __attribute__((ext_vector_type(4))) float floatx4;  // MFMA acc

// ---------------- GCN prep (identical to round-10 verified version) ----------------

__global__ void count_kernel(const int* __restrict__ idx, int E, int* __restrict__ cnt) {
    int e = (blockIdx.x * blockDim.x + threadIdx.x) * 4;
    if (((E & 3) == 0) && e + 3 < E) {
        int4 d = *(const int4*)(idx + E + e);   // 16B aligned: E%4==0, e%4==0
        atomicAdd(&cnt[d.x], 1);
        atomicAdd(&cnt[d.y], 1);
        atomicAdd(&cnt[d.z], 1);
        atomicAdd(&cnt[d.w], 1);
    } else {
        int lim = min(e + 4, E);
        for (int k = e; k < lim; ++k) atomicAdd(&cnt[idx[E + k]], 1);
    }
}

// Fixed-point pack: q = rn(v * 2^21), biased +2^26 per 32b field -> every added term
// positive and < 2^26.2, no cross-field carry up to ~56 adds. ONE u64 atomic per
// edge; dinv[src] computed inline from the deg gather (scatter is atomic-rate-bound).
__device__ __forceinline__ unsigned long long pk2(float xx, float yy, float dv) {
    int qx = __float2int_rn(xx * dv * 2097152.0f);
    int qy = __float2int_rn(yy * dv * 2097152.0f);
    return ((unsigned long long)(unsigned)(qx + (1 << 26)) << 32) |
           (unsigned)(qy + (1 << 26));
}

__global__ void scatter_pk_kernel(const int* __restrict__ idx, int E,
                                  const float2* __restrict__ x2,
                                  const int* __restrict__ deg,
                                  unsigned long long* __restrict__ aggP) {
    int e = (blockIdx.x * blockDim.x + threadIdx.x) * 4;
    if (((E & 3) == 0) && e + 3 < E) {
        int4 s = *(const int4*)(idx + e);
        int4 d = *(const int4*)(idx + E + e);
        float2 v0 = x2[s.x];
        float2 v1 = x2[s.y];
        float2 v2 = x2[s.z];
        float2 v3 = x2[s.w];
        float dv0 = rsqrtf((float)deg[s.x] + 1.0f);
        float dv1 = rsqrtf((float)deg[s.y] + 1.0f);
        float dv2 = rsqrtf((float)deg[s.z] + 1.0f);
        float dv3 = rsqrtf((float)deg[s.w] + 1.0f);
        atomicAdd(&aggP[d.x], pk2(v0.x, v0.y, dv0));
        atomicAdd(&aggP[d.y], pk2(v1.x, v1.y, dv1));
        atomicAdd(&aggP[d.z], pk2(v2.x, v2.y, dv2));
        atomicAdd(&aggP[d.w], pk2(v3.x, v3.y, dv3));
    } else {
        int lim = min(e + 4, E);
        for (int k = e; k < lim; ++k) {
            int s = idx[k];
            int d = idx[E + k];
            float2 v = x2[s];
            float dv = rsqrtf((float)deg[s] + 1.0f);
            atomicAdd(&aggP[d], pk2(v.x, v.y, dv));
        }
    }
}

// -------- MFMA LSTM: OPERAND-SWAPPED gates^T = [x;h].W^T, lane-local cell --------
// r10 structure (verified, 210 us) + VALU de-duplication: xg is now computed ONCE
// (wave t1 computes its own 4 units 16t1+4q..+3 of node n; r10 had BOTH waves
// compute all 8 of each lane's frag in registers) and exchanged through the same
// parity-indexed conflict-free LDS pattern as h. Per-step VALU drops ~28 instr/wave
// (the binding resource: VALUBusy 55% >> MfmaUtil 25%). The xg x-term MFMA chain
// now reads LDS like the h-chain (reads issue together, latency parallel).
// ONE barrier/step still covers both h(t) and xg(t+1) (both written to parity P^1
// before the barrier, read next step at P^1). Also fixes r10's latent race:
// xg(0) prologue now sits behind an explicit barrier after ubuf staging.

__device__ __forceinline__ float sg(float y) {       // sigmoid, exp2-prescaled input
    return __builtin_amdgcn_rcpf(1.0f + __builtin_amdgcn_exp2f(-y));
}
__device__ __forceinline__ float tanh_f(float x) {   // unscaled input
    return fmaf(__builtin_amdgcn_rcpf(1.0f + __expf(-2.0f * x)), 2.0f, -1.0f);
}
// truncation split: f = hi + lo (~2^-16 rel); 3-term MFMA keeps fp32-like precision
__device__ __forceinline__ void fsplit(float f, short& hi, short& lo) {
    unsigned u = __float_as_uint(f);
    hi = (short)(u >> 16);
    float r = f - __uint_as_float(u & 0xFFFF0000u);
    lo = (short)(__float_as_uint(r) >> 16);
}
// pair split via v_perm_b32 (verified r9/r10): hi word = (hi16(b)<<16)|hi16(a)
__device__ __forceinline__ void fsplit2(float a, float b, unsigned& hi, unsigned& lo) {
    unsigned ta = __float_as_uint(a) & 0xFFFF0000u;
    unsigned tb = __float_as_uint(b) & 0xFFFF0000u;
    float ra = a - __uint_as_float(ta);
    float rb = b - __uint_as_float(tb);
    hi = __builtin_amdgcn_perm(__float_as_uint(b), __float_as_uint(a), 0x07060302u);
    lo = __builtin_amdgcn_perm(__float_as_uint(rb), __float_as_uint(ra), 0x07060302u);
}

__global__ __launch_bounds__(TPB2, 3) void lstm_sw3_kernel(
    const float2* __restrict__ x2,
    const unsigned long long* __restrict__ aggP, const int* __restrict__ deg,
    int N,
    const float* __restrict__ gcn_W, const float* __restrict__ gcn_b,
    const float* __restrict__ w_ih, const float* __restrict__ w_hh,
    const float* __restrict__ b_ih, const float* __restrict__ b_hh,
    const float* __restrict__ fc_W, const float* __restrict__ fc_b,
    float* __restrict__ out) {
    __shared__ float2 ubuf[16][SEQ + 1];                  // 16.5 KB; col 128 = zero pad
    __shared__ __align__(16) short hhb[2][16][XS];        // h hi [parity][node][unit]
    __shared__ __align__(16) short hlb[2][16][XS];        // h lo
    __shared__ __align__(16) short xgh[2][16][XS];        // xg hi [parity][node][unit]
    __shared__ __align__(16) short xgl[2][16][XS];        // xg lo
    __shared__ float fcp[2][16];

    const int tid = threadIdx.x;
    const int t1 = tid >> 6;       // wave id == unit-half
    const int lane = tid & 63;
    const int n = lane & 15;       // A-row (node) / C-col (unit) / B-col (gate-row)
    const int q = lane >> 4;       // k-slice / C-row-group
    const int base = blockIdx.x * 16;

    // ---- stage u[node][t] = dv*(agg + x*dv) into LDS (coalesced, 16 iters) ----
    {
        const float2* xb = x2 + (size_t)base * SEQ;
        const unsigned long long* apb = aggP + (size_t)base * SEQ;
        const int* dgb = deg + (size_t)base * SEQ;
        const int lim = min(16 * SEQ, (N - base) * SEQ);
        for (int i = tid; i < 16 * SEQ; i += TPB2) {
            float2 v = make_float2(0.f, 0.f);
            if (i < lim) {
                int dg = dgb[i];
                float dv = rsqrtf((float)dg + 1.0f);
                float2 xx = xb[i];
                unsigned long long pk = apb[i];
                unsigned bias = (unsigned)dg * 67108864u;  // deg * 2^26
                float ax = (float)((int)((unsigned)(pk >> 32) - bias)) * (1.0f / 2097152.0f);
                float ay = (float)((int)((unsigned)pk - bias)) * (1.0f / 2097152.0f);
                v = make_float2(dv * fmaf(xx.x, dv, ax), dv * fmaf(xx.y, dv, ay));
            }
            ubuf[i >> 7][i & 127] = v;
        }
        if (tid < 16) ubuf[tid][SEQ] = make_float2(0.f, 0.f);
        // zero h parity-0 buffers (read at t=0): 320+320 dwords
        for (int i = tid; i < 320; i += TPB2) {
            ((int*)hhb[0])[i] = 0;
            ((int*)hlb[0])[i] = 0;
        }
    }

    // ---- W B-frags: 4 gate-tiles for unit-half t1, hi/lo bf16, exp2-scale folded ----
    short8 WiH[4], WiL[4], WhH[4], WhL[4];
    floatx4 biasv[4];
    #pragma unroll
    for (int g = 0; g < 4; ++g) {
        const float gsc = (g == 2) ? 2.8853900817779268f : 1.4426950408889634f;
        const int arow = g * 32 + 16 * t1 + n;   // B-frag col index = lane&15
        const float* wi = w_ih + arow * HID + 8 * q;
        const float* wh = w_hh + arow * HID + 8 * q;
        #pragma unroll
        for (int j = 0; j < 8; ++j) {
            short h16, l16;
            fsplit(wi[j] * gsc, h16, l16); WiH[g][j] = h16; WiL[g][j] = l16;
            fsplit(wh[j] * gsc, h16, l16); WhH[g][j] = h16; WhL[g][j] = l16;
        }
        const float bb = (b_ih[arow] + b_hh[arow]) * gsc;   // C-col bias: same for all rows
        biasv[g] = (floatx4){bb, bb, bb, bb};
    }

    // ---- GCN consts for this lane's OWN xg units: uo = 16*t1 + 4*q + k ----
    float wgo0[4], wgo1[4], gbo[4];
    #pragma unroll
    for (int k = 0; k < 4; ++k) {
        const int uo = 16 * t1 + 4 * q + k;
        wgo0[k] = gcn_W[uo];
        wgo1[k] = gcn_W[HID + uo];
        gbo[k] = gcn_b[uo];
    }
    const float fcw = fc_W[16 * t1 + n];   // lane's output unit

    float c[4] = {0.f, 0.f, 0.f, 0.f};
    float ho[4] = {0.f, 0.f, 0.f, 0.f};

// own-unit xg for time TT written to parity PAR: 4 relu chains + 2 fsplit2 + 2 b64
#define OWN_XG(PAR, TT)                                                           \
    {                                                                             \
        float2 uu = ubuf[n][TT];                                                  \
        float gv[4];                                                              \
        _Pragma("unroll") for (int k = 0; k < 4; ++k)                             \
            gv[k] = fmaxf(fmaf(uu.x, wgo0[k], fmaf(uu.y, wgo1[k], gbo[k])), 0.f); \
        unsigned hp0, lp0, hp1, lp1;                                              \
        fsplit2(gv[0], gv[1], hp0, lp0);                                          \
        fsplit2(gv[2], gv[3], hp1, lp1);                                          \
        uint2 th = make_uint2(hp0, hp1);                                          \
        uint2 tl = make_uint2(lp0, lp1);                                          \
        *(uint2*)&xgh[PAR][n][16 * t1 + 4 * q] = th;                              \
        *(uint2*)&xgl[PAR][n][16 * t1 + 4 * q] = tl;                              \
    }

    __syncthreads();   // ubuf + h-zero staged (both waves)
    OWN_XG(0, 0);      // xg(0) -> parity 0
    __syncthreads();   // xg(0) visible

// One step, compile-time parity P: reads h(t-1)+xg(t) from buf P, writes
// h(t)+xg(t+1) to buf P^1, ONE barrier. Swapped MFMA, chain of 6 (x then h terms;
// x-terms fill the LDS read latency window, h-terms extend the chain after).
#define LSTM_STEP(P, TT)                                                                    \
    do {                                                                                    \
        const short8 xh = *(const short8*)&xgh[P][n][8 * q];                                \
        const short8 xl = *(const short8*)&xgl[P][n][8 * q];                                \
        const short8 hh = *(const short8*)&hhb[P][n][8 * q];                                \
        const short8 hl = *(const short8*)&hlb[P][n][8 * q];                                \
        floatx4 acc[4];                                                                     \
        __builtin_amdgcn_s_setprio(1);                                                      \
        _Pragma("unroll") for (int g = 0; g < 4; ++g)                                       \
            acc[g] = __builtin_amdgcn_mfma_f32_16x16x32_bf16(xh, WiH[g], biasv[g], 0, 0, 0); \
        _Pragma("unroll") for (int g = 0; g < 4; ++g)                                       \
            acc[g] = __builtin_amdgcn_mfma_f32_16x16x32_bf16(xh, WiL[g], acc[g], 0, 0, 0);  \
        _Pragma("unroll") for (int g = 0; g < 4; ++g)                                       \
            acc[g] = __builtin_amdgcn_mfma_f32_16x16x32_bf16(xl, WiH[g], acc[g], 0, 0, 0);  \
        _Pragma("unroll") for (int g = 0; g < 4; ++g)                                       \
            acc[g] = __builtin_amdgcn_mfma_f32_16x16x32_bf16(hh, WhH[g], acc[g], 0, 0, 0);  \
        _Pragma("unroll") for (int g = 0; g < 4; ++g)                                       \
            acc[g] = __builtin_amdgcn_mfma_f32_16x16x32_bf16(hh, WhL[g], acc[g], 0, 0, 0);  \
        _Pragma("unroll") for (int g = 0; g < 4; ++g)                                       \
            acc[g] = __builtin_amdgcn_mfma_f32_16x16x32_bf16(hl, WhH[g], acc[g], 0, 0, 0);  \
        __builtin_amdgcn_s_setprio(0);                                                      \
        OWN_XG((P) ^ 1, (TT) + 1); /* xg(t+1); overlaps MFMA latency; pre-barrier */        \
        _Pragma("unroll") for (int r = 0; r < 4; ++r) {                                     \
            const float ig = sg(acc[0][r]);                                                 \
            const float fg = sg(acc[1][r]);                                                 \
            const float gg = fmaf(sg(acc[2][r]), 2.0f, -1.0f);                              \
            const float og = sg(acc[3][r]);                                                 \
            c[r] = fmaf(fg, c[r], ig * gg);                                                 \
            const float hv = og * tanh_f(c[r]);                                             \
            ho[r] = hv;                                                                     \
            short h16, l16;                                                                 \
            fsplit(hv, h16, l16);                                                           \
            hhb[(P) ^ 1][4 * q + r][16 * t1 + n] = h16;                                     \
            hlb[(P) ^ 1][4 * q + r][16 * t1 + n] = l16;                                     \
        }                                                                                   \
        __syncthreads();                                                                    \
    } while (0)

    #pragma unroll 1
    for (int t = 0; t < SEQ; t += 2) {
        LSTM_STEP(0, t);        // reads parity 0, writes parity 1
        LSTM_STEP(1, t + 1);    // reads parity 1, writes parity 0
    }
#undef LSTM_STEP
#undef OWN_XG

    // ---- FC epilogue: lane holds h(127) of unit 16t1+n, nodes 4q+r ----
    float p0 = ho[0] * fcw, p1 = ho[1] * fcw, p2 = ho[2] * fcw, p3 = ho[3] * fcw;
    #pragma unroll
    for (int m = 1; m < 16; m <<= 1) {   // reduce over the 16 unit-lanes (same q)
        p0 += __shfl_xor(p0, m);
        p1 += __shfl_xor(p1, m);
        p2 += __shfl_xor(p2, m);
        p3 += __shfl_xor(p3, m);
    }
    if (n == 0) {
        fcp[t1][4 * q + 0] = p0;
        fcp[t1][4 * q + 1] = p1;
        fcp[t1][4 * q + 2] = p2;
        fcp[t1][4 * q + 3] = p3;
    }
    __syncthreads();
    if (t1 == 0 && lane < 16) {
        const int node = base + lane;
        if (node < N) out[node] = fcp[0][lane] + fcp[1][lane] + fc_b[0];
    }
}

extern "C" void kernel_launch(void* const* d_in, const int* in_sizes, int n_in,
                              void* d_out, int out_size, void* d_ws, size_t ws_size,
                              hipStream_t stream) {
    const float* x     = (const float*)d_in[0];
    const int*   idx   = (const int*)d_in[1];
    const float* gcn_W = (const float*)d_in[2];
    const float* gcn_b = (const float*)d_in[3];
    const float* w_ih  = (const float*)d_in[4];
    const float* w_hh  = (const float*)d_in[5];
    const float* b_ih  = (const float*)d_in[6];
    const float* b_hh  = (const float*)d_in[7];
    const float* fc_W  = (const float*)d_in[8];
    const float* fc_b  = (const float*)d_in[9];

    const int num_nodes = in_sizes[0] / (SEQ * 2);
    const int ntot = num_nodes * SEQ;
    const int E = in_sizes[1] / 2;

    // workspace: deg[ntot i32] | aggP[ntot u64]  (3 planes of 4B)
    int* deg = (int*)d_ws;
    unsigned long long* aggP = (unsigned long long*)((char*)d_ws + (size_t)ntot * 4);

    hipMemsetAsync(d_ws, 0, (size_t)ntot * 12, stream);

    const int eb = (E + 1023) / 1024;  // 4 edges/thread, 256 threads/block
    count_kernel<<<eb, 256, 0, stream>>>(idx, E, deg);
    scatter_pk_kernel<<<eb, 256, 0, stream>>>(idx, E, (const float2*)x, deg, aggP);
    lstm_sw3_kernel<<<(num_nodes + 15) / 16, TPB2, 0, stream>>>(
        (const float2*)x, aggP, deg, num_nodes,
        gcn_W, gcn_b, w_ih, w_hh, b_ih, b_hh, fc_W, fc_b,
        (float*)d_out);
}